// Round 13
// baseline (295.458 us; speedup 1.0000x reference)
//
#include <hip/hip_runtime.h>
#include <hip/hip_bf16.h>

// GraphSAGEConv: N=50000 nodes, E=800000 edges, D=64 in/out, fp32.
// out = x @ W_self^T + b_self + scatter_mean(x[col] -> row) @ W_neigh^T + b_neigh
//
// R13: single-writer-line build. R11's build_k (54 us) was bound by slot-store
// line ping-pong (each 2B store from a random XCD = 64B writeback; 51 MB).
// R12's XCD-affinity queues failed (8x read amplification, 128 us). Fix:
//  P1 partition_k: edges -> 196 node-range buckets; LDS-staged, flushed in
//     full 16-entry (64B) aligned groups -> every bucket line written once by
//     one wave. + x->bf16 cast.
//  P2 bucket_k: one block per bucket bins its <=4800 entries in LDS, writes
//     cnt+slots coalesced (single-writer).
//  P3 fused_k: R11-proven gather+MFMA (CAP 48).
// ws ~15.2 MB; if ws_size is smaller, fall back to R11-proven direct build
// (branch on ws_size = constant per session -> same work every call).

#define D      64
#define CAP    48      // slots per node; P(Poisson(16) > 48) ~ 1e-11
#define TPB    256
#define WPB    4       // waves per block in fused_k
#define TPW    16      // nodes per wave tile (MFMA M)
#define BUFCAP 32      // LDS staging entries per bucket
#define CAPB   4800    // bucket capacity (mean 4082, +11 sigma)
#define PBLK   224     // partition blocks
#define EPT    4       // edges per thread per round

typedef __attribute__((ext_vector_type(8))) short bf16x8;
typedef __attribute__((ext_vector_type(4))) float f32x4;

__device__ __forceinline__ unsigned short f2bf(float f) {   // fp32->bf16 RNE
    unsigned u = __float_as_uint(f);
    return (unsigned short)((u + 0x7fffu + ((u >> 16) & 1u)) >> 16);
}
__device__ __forceinline__ float bf2f(unsigned short s) {
    return __uint_as_float((unsigned)s << 16);
}
__device__ __forceinline__ int load_idx(const void* ei, int use64, long long pos) {
    if (use64) return (int)((const long long*)ei)[pos];
    return ((const int*)ei)[pos];
}

// ---- init: zero gcur + dtype detect ----------------------------------------
__global__ __launch_bounds__(256) void init_k(
        const long long* __restrict__ ei, int* __restrict__ gcur,
        int* __restrict__ flag, int N, int NB2) {
    int t = threadIdx.x;
    if (t < NB2) gcur[t] = 0;
    if (t < 64) {
        long long v = (t < 16) ? ei[t] : 0;
        unsigned long long bad = __ballot(t < 16 && (v < 0 || v >= (long long)N));
        if (t == 0) *flag = (bad == 0ULL) ? 1 : 0;
    }
}

// ---- P1: partition edges into node-range buckets (single-writer lines) -----
__global__ __launch_bounds__(256) void partition_k(
        const float* __restrict__ x, const void* __restrict__ ei,
        const int* __restrict__ flag, unsigned short* __restrict__ xb,
        int* __restrict__ gcur, int* __restrict__ bkt,
        int N, int E, int NB2) {
    __shared__ int lcnt[256];
    __shared__ int buf[256][BUFCAP];

    const int t = threadIdx.x, b = blockIdx.x;
    const int NT = gridDim.x * 256;
    const int use64 = *flag;

    // cast x -> bf16 (independent grid-stride, no barriers)
    int NV = (N * D) >> 2;
    for (int i = b * 256 + t; i < NV; i += NT) {
        float4 v = *(const float4*)&x[i * 4];
        ushort4 o;
        o.x = f2bf(v.x); o.y = f2bf(v.y); o.z = f2bf(v.z); o.w = f2bf(v.w);
        *(ushort4*)&xb[i * 4] = o;
    }

    lcnt[t] = 0;
    __syncthreads();

    const int perround = NT * EPT;
    const int nrounds = (E + perround - 1) / perround;
    const int wv = t >> 6, ln = t & 63;

    for (int rr = 0; rr < nrounds; ++rr) {
        // append EPT edges per thread into LDS buckets
        #pragma unroll
        for (int j = 0; j < EPT; ++j) {
            long long e = (long long)rr * perround + (b * EPT + j) * 256 + t;
            if (e < E) {
                int r = load_idx(ei, use64, e);
                int c = load_idx(ei, use64, (long long)E + e);
                int bk = r >> 8;
                int entry = ((r & 255) << 16) | c;
                int pos = atomicAdd(&lcnt[bk], 1);
                if (pos < BUFCAP) buf[bk][pos] = entry;
                else {                                   // rare spill
                    atomicSub(&lcnt[bk], 1);
                    int g = atomicAdd(&gcur[bk], 1);
                    if (g < CAPB) bkt[bk * CAPB + g] = entry;
                }
            }
        }
        __syncthreads();
        // flush full 16-entry groups (aligned 64B lines, single writer)
        for (int bk = wv; bk < NB2; bk += 4) {
            int k = lcnt[bk];
            int g = k & ~15;
            if (g > 0) {
                int base = 0;
                if (ln == 0) base = atomicAdd(&gcur[bk], g);
                base = __shfl(base, 0);
                if (ln < g) {
                    int idx = base + ln;
                    if (idx < CAPB) bkt[bk * CAPB + idx] = buf[bk][ln];
                }
                int rem = k - g;
                int tmp = (ln < rem) ? buf[bk][g + ln] : 0;
                if (ln < rem) buf[bk][ln] = tmp;
                if (ln == 0) lcnt[bk] = rem;
            }
        }
        __syncthreads();
    }
    // final flush of remainders (partial lines, ~2-3 entries/bucket/block)
    for (int bk = wv; bk < NB2; bk += 4) {
        int k = lcnt[bk];
        if (k > 0) {
            int base = 0;
            if (ln == 0) base = atomicAdd(&gcur[bk], k);
            base = __shfl(base, 0);
            if (ln < k) {
                int idx = base + ln;
                if (idx < CAPB) bkt[bk * CAPB + idx] = buf[bk][ln];
            }
        }
    }
}

// ---- P2: per-bucket LDS binning -> coalesced cnt+slots ---------------------
__global__ __launch_bounds__(256) void bucket_k(
        const int* __restrict__ gcur, const int* __restrict__ bkt,
        int* __restrict__ cnt, unsigned short* __restrict__ slots, int N) {
    __shared__ unsigned short sl[256 * CAP];   // 24 KB
    __shared__ int lc[256];
    const int b = blockIdx.x, t = threadIdx.x;
    lc[t] = 0;
    __syncthreads();
    int k = gcur[b]; if (k > CAPB) k = CAPB;
    for (int i = t; i < k; i += 256) {
        int entry = bkt[b * CAPB + i];
        int lr = entry >> 16;
        int c  = entry & 0xFFFF;
        int pos = atomicAdd(&lc[lr], 1);
        if (pos < CAP) sl[lr * CAP + pos] = (unsigned short)c;
    }
    __syncthreads();
    int node = b * 256 + t;
    if (node < N) cnt[node] = lc[t];
    const int* sli = (const int*)sl;
    int* gsl = (int*)(slots + (size_t)b * 256 * CAP);
    for (int i = t; i < 256 * CAP / 2; i += 256) gsl[i] = sli[i];
}

// ---- R11-proven fallback build (used only if ws too small) -----------------
__global__ __launch_bounds__(256) void fb_init_k(
        const long long* __restrict__ ei, const float* __restrict__ x,
        unsigned short* __restrict__ xb, int* __restrict__ cnt,
        int* __restrict__ flag, int N) {
    int tid = blockIdx.x * 256 + threadIdx.x;
    int NT  = gridDim.x * 256;
    for (int i = tid; i < N; i += NT) cnt[i] = 0;
    if (tid < 64) {
        long long v = (tid < 16) ? ei[tid] : 0;
        unsigned long long bad = __ballot(tid < 16 && (v < 0 || v >= (long long)N));
        if (tid == 0) *flag = (bad == 0ULL) ? 1 : 0;
    }
    int NV = (N * D) >> 2;
    for (int i = tid; i < NV; i += NT) {
        float4 v = *(const float4*)&x[i * 4];
        ushort4 o;
        o.x = f2bf(v.x); o.y = f2bf(v.y); o.z = f2bf(v.z); o.w = f2bf(v.w);
        *(ushort4*)&xb[i * 4] = o;
    }
}

__global__ __launch_bounds__(256) void fb_build_k(
        const void* __restrict__ ei, const int* __restrict__ flag,
        int* __restrict__ cnt, unsigned short* __restrict__ slots, int E) {
    int e = blockIdx.x * 256 + threadIdx.x;
    if (e >= E) return;
    int use64 = *flag;
    int r = load_idx(ei, use64, e);
    int c = load_idx(ei, use64, (long long)E + e);
    int pos = atomicAdd(&cnt[r], 1);
    if (pos < CAP) slots[r * CAP + pos] = (unsigned short)c;
}

// ---- fused gather-mean (bf16 rows) + MFMA dual linear (R11-proven) ---------
__global__ __launch_bounds__(TPB) void fused_k(
        const unsigned short* __restrict__ xb,
        const int* __restrict__ cnt, const unsigned short* __restrict__ slots,
        const float* __restrict__ Ws, const float* __restrict__ bs,
        const float* __restrict__ Wn, const float* __restrict__ bn,
        float* __restrict__ out, int N) {
    __shared__ __align__(16) short wcat[D][136];         // WcatT[f][kk] bf16
    __shared__ __align__(16) short mtile[WPB][TPW][72];  // per-wave mean tiles

    const int t = threadIdx.x;
    for (int i = t; i < D * 128; i += TPB) {   // stage [Ws | Wn] rows, bf16
        int f = i >> 7, kk = i & 127;
        float v = (kk < D) ? Ws[f * D + kk] : Wn[f * D + (kk - D)];
        wcat[f][kk] = (short)f2bf(v);
    }
    __syncthreads();   // only barrier; waves independent afterwards

    const int w    = t >> 6;
    const int lane = t & 63;
    const int m_   = lane & 15;
    const int quad = lane >> 4;
    const int ql   = m_;            // gather lane-in-quarter
    const int q4   = quad;          // quarter -> node slot

    int tile = (blockIdx.x * WPB + w) * TPW;
    if (tile >= N) return;

    // ---- gather phase ----
    for (int p = 0; p < 4; ++p) {
        int n = tile + p * 4 + q4;
        int deg = (n < N) ? cnt[n] : 0;
        int mm = deg < CAP ? deg : CAP;
        float4 s = make_float4(0.f, 0.f, 0.f, 0.f);
        for (int base = 0; base < mm; base += 16) {
            int sv = (base + ql < mm) ? (int)slots[n * CAP + base + ql] : 0;
            int mq = mm - base; if (mq > 16) mq = 16;
            for (int j = 0; j < mq; ++j) {
                int c = __shfl(sv, (q4 << 4) + j);
                ushort4 v = *(const ushort4*)&xb[c * D + 4 * ql];   // 8B
                s.x += bf2f(v.x); s.y += bf2f(v.y);
                s.z += bf2f(v.z); s.w += bf2f(v.w);
            }
        }
        float dinv = (deg > 0) ? 1.0f / (float)deg : 0.0f;
        short4 mv;
        mv.x = (short)f2bf(s.x * dinv); mv.y = (short)f2bf(s.y * dinv);
        mv.z = (short)f2bf(s.z * dinv); mv.w = (short)f2bf(s.w * dinv);
        *(short4*)&mtile[w][p * 4 + q4][4 * ql] = mv;   // 8B, wave-local
    }

    // ---- A fragments: ks 0,1 direct bf16 from xb; ks 2,3 from mean LDS -----
    int nrow = tile + m_;
    const unsigned short* xr = xb + (size_t)(nrow < N ? nrow : 0) * D;
    bf16x8 afrag[4];
    afrag[0] = *(const bf16x8*)&xr[quad * 8];
    afrag[1] = *(const bf16x8*)&xr[32 + quad * 8];
    #pragma unroll
    for (int ks = 2; ks < 4; ++ks)
        afrag[ks] = *(const bf16x8*)&mtile[w][m_][(ks - 2) * 32 + quad * 8];

    // ---- MFMA: 4 f-tiles x 4 k-steps ----
    f32x4 acc[4];
    #pragma unroll
    for (int nf = 0; nf < 4; ++nf) {
        int fcol = nf * 16 + m_;
        float bsum = bs[fcol] + bn[fcol];
        acc[nf] = (f32x4){bsum, bsum, bsum, bsum};
    }
    #pragma unroll
    for (int nf = 0; nf < 4; ++nf) {
        #pragma unroll
        for (int ks = 0; ks < 4; ++ks) {
            bf16x8 bfr = *(const bf16x8*)&wcat[nf * 16 + m_][ks * 32 + quad * 8];
            acc[nf] = __builtin_amdgcn_mfma_f32_16x16x32_bf16(
                afrag[ks], bfr, acc[nf], 0, 0, 0);
        }
    }

    // ---- store: row = quad*4 + reg, col = nf*16 + m_ ----
    #pragma unroll
    for (int nf = 0; nf < 4; ++nf) {
        int fcol = nf * 16 + m_;
        #pragma unroll
        for (int r = 0; r < 4; ++r) {
            int node = tile + quad * 4 + r;
            if (node < N) out[(size_t)node * D + fcol] = acc[nf][r];
        }
    }
}

// ================= host launcher ============================================
extern "C" void kernel_launch(void* const* d_in, const int* in_sizes, int n_in,
                              void* d_out, int out_size, void* d_ws, size_t ws_size,
                              hipStream_t stream) {
    const float* x  = (const float*)d_in[0];
    const void*  ei = d_in[1];
    const float* Ws = (const float*)d_in[2];
    const float* bs = (const float*)d_in[3];
    const float* Wn = (const float*)d_in[4];
    const float* bn = (const float*)d_in[5];
    float* out = (float*)d_out;

    int N   = in_sizes[0] / D;
    int E   = in_sizes[1] / 2;
    int NB2 = (N + 255) >> 8;                 // 196 node-range buckets (<=256)

    size_t xb_b    = (size_t)N * D * 2;                 // 6,400,000
    size_t slots_b = (size_t)NB2 * 256 * CAP * 2;       // 4,816,896
    size_t cnt_b   = (size_t)NB2 * 256 * 4;             //   200,704
    size_t bkt_b   = (size_t)NB2 * CAPB * 4;            // 3,763,200

    unsigned short* xb    = (unsigned short*)d_ws;
    unsigned short* slots = (unsigned short*)((char*)d_ws + xb_b);
    int*            cnt   = (int*)((char*)d_ws + xb_b + slots_b);
    int*            bkt   = (int*)((char*)d_ws + xb_b + slots_b + cnt_b);
    int*            gcur  = bkt + (size_t)NB2 * CAPB;
    int*            flag  = gcur + NB2;

    size_t need_big = xb_b + slots_b + cnt_b + bkt_b + (NB2 + 1) * 4;

    if (ws_size >= need_big) {
        init_k<<<1, 256, 0, stream>>>((const long long*)ei, gcur, flag, N, NB2);
        partition_k<<<PBLK, 256, 0, stream>>>(x, ei, flag, xb, gcur, bkt, N, E, NB2);
        bucket_k<<<NB2, 256, 0, stream>>>(gcur, bkt, cnt, slots, N);
    } else {
        // R11-proven direct build (fits in ~11.5 MB)
        int* fcnt  = (int*)((char*)d_ws + xb_b + slots_b);
        int* fflag = fcnt + (size_t)NB2 * 256;
        fb_init_k<<<784, 256, 0, stream>>>((const long long*)ei, x, xb, fcnt,
                                           fflag, N);
        fb_build_k<<<(E + 255) / 256, 256, 0, stream>>>(ei, fflag, fcnt, slots, E);
        cnt = fcnt;
    }

    int ntiles  = (N + TPW - 1) / TPW;        // 3125
    int fblocks = (ntiles + WPB - 1) / WPB;   // 782
    fused_k<<<fblocks, TPB, 0, stream>>>(xb, cnt, slots, Ws, bs, Wn, bn, out, N);
}

// Round 14
// 184.553 us; speedup vs baseline: 1.6009x; 1.6009x over previous
//
#include <hip/hip_runtime.h>
#include <hip/hip_bf16.h>

// GraphSAGEConv: N=50000 nodes, E=800000 edges, D=64 in/out, fp32.
// out = x @ W_self^T + b_self + scatter_mean(x[col] -> row) @ W_neigh^T + b_neigh
//
// R14 = R11 (proven 167 us) consolidated to 2 kernels + 1 DMA memset:
//   - cnt zeroed by hipMemsetAsync (was: init_k, a 784-block kernel)
//   - edge-index dtype flag computed inline per block (uniform scalar loads)
//   - build_k / fused_k otherwise byte-identical to R11.
// Build is scattered-write-ceiling bound (51 MB line ping-pong, 54 us);
// R12 (XCD queues) and R13 (LDS bucket sort) both proved software
// reordering costs more than the ping-pong itself. Fused is scattered-read
// bound (~45 MB @ ~1.7 TB/s random-line BW).
//
// ws layout: [xb: N*D ushort][slots: N*60 ushort][cnt: N int] = 12.6 MB

#define D   64
#define CAP 60     // slots per node; P(Poisson(16) > 60) ~ 1e-18; mean uses full cnt
#define TPB 256
#define WPB 4      // waves per block in fused_k
#define TPW 16     // nodes per wave tile (MFMA M)

typedef __attribute__((ext_vector_type(8))) short bf16x8;
typedef __attribute__((ext_vector_type(4))) float f32x4;

__device__ __forceinline__ unsigned short f2bf(float f) {   // fp32->bf16 RNE
    unsigned u = __float_as_uint(f);
    return (unsigned short)((u + 0x7fffu + ((u >> 16) & 1u)) >> 16);
}
__device__ __forceinline__ float bf2f(unsigned short s) {
    return __uint_as_float((unsigned)s << 16);
}

// Inline dtype detect: reference declares edge_index int64, harness may pass
// int32. int32 read as int64 falls outside [0,N) with p ~ 1 - 1e-20 over 16
// probes. Uniform across all threads -> scalar loads, ~free.
__device__ __forceinline__ int detect_use64(const void* ei, int N) {
    const long long* p = (const long long*)ei;
    int use64 = 1;
    #pragma unroll
    for (int i = 0; i < 16; ++i) {
        long long v = p[i];
        if (v < 0 || v >= (long long)N) { use64 = 0; break; }
    }
    return use64;
}

__device__ __forceinline__ int load_idx(const void* ei, int use64, long long pos) {
    if (use64) return (int)((const long long*)ei)[pos];
    return ((const int*)ei)[pos];
}

// ---- build: bucket edges (hist+place fused) + cast x -> bf16 ---------------
__global__ __launch_bounds__(256) void build_k(
        const float* __restrict__ x, const void* __restrict__ ei,
        int* __restrict__ cnt, unsigned short* __restrict__ slots,
        unsigned short* __restrict__ xb, int N, int E) {
    int tid = blockIdx.x * 256 + threadIdx.x;
    int NT  = gridDim.x * 256;
    int use64 = detect_use64(ei, N);
    for (int e = tid; e < E; e += NT) {
        int r = load_idx(ei, use64, e);
        int c = load_idx(ei, use64, (long long)E + e);
        int pos = atomicAdd(&cnt[r], 1);
        if (pos < CAP) slots[r * CAP + pos] = (unsigned short)c;
    }
    int NV = (N * D) >> 2;                     // float4 groups
    for (int i = tid; i < NV; i += NT) {
        float4 v = *(const float4*)&x[i * 4];
        ushort4 o;
        o.x = f2bf(v.x); o.y = f2bf(v.y); o.z = f2bf(v.z); o.w = f2bf(v.w);
        *(ushort4*)&xb[i * 4] = o;
    }
}

// ---- fused gather-mean (bf16 rows) + MFMA dual linear (R11-proven) ---------
// Wave owns 16 nodes (4 passes x quarter-wave/node). Quarter-wave lane ql
// loads ushort4 (8B) of the neighbor row: 16 lanes x 8B = 128B = full bf16
// row. Then D = A(16x128 bf16: [xb | mean]) x WcatT + bias via 16 MFMA.
// Layouts (R9-R11 proven): A[m=lane&15][k=quad*8+j], B[k][n=lane&15],
// C/D col=lane&15 row=quad*4+reg.
__global__ __launch_bounds__(TPB) void fused_k(
        const unsigned short* __restrict__ xb,
        const int* __restrict__ cnt, const unsigned short* __restrict__ slots,
        const float* __restrict__ Ws, const float* __restrict__ bs,
        const float* __restrict__ Wn, const float* __restrict__ bn,
        float* __restrict__ out, int N) {
    __shared__ __align__(16) short wcat[D][136];         // WcatT[f][kk] bf16
    __shared__ __align__(16) short mtile[WPB][TPW][72];  // per-wave mean tiles

    const int t = threadIdx.x;
    for (int i = t; i < D * 128; i += TPB) {   // stage [Ws | Wn] rows, bf16
        int f = i >> 7, kk = i & 127;
        float v = (kk < D) ? Ws[f * D + kk] : Wn[f * D + (kk - D)];
        wcat[f][kk] = (short)f2bf(v);
    }
    __syncthreads();   // only barrier; waves independent afterwards

    const int w    = t >> 6;
    const int lane = t & 63;
    const int m_   = lane & 15;
    const int quad = lane >> 4;
    const int ql   = m_;            // gather lane-in-quarter
    const int q4   = quad;          // quarter -> node slot

    int tile = (blockIdx.x * WPB + w) * TPW;
    if (tile >= N) return;

    // ---- gather phase ----
    for (int p = 0; p < 4; ++p) {
        int n = tile + p * 4 + q4;
        int deg = (n < N) ? cnt[n] : 0;
        int mm = deg < CAP ? deg : CAP;
        float4 s = make_float4(0.f, 0.f, 0.f, 0.f);
        for (int base = 0; base < mm; base += 16) {
            int sv = (base + ql < mm) ? (int)slots[n * CAP + base + ql] : 0;
            int mq = mm - base; if (mq > 16) mq = 16;
            for (int j = 0; j < mq; ++j) {
                int c = __shfl(sv, (q4 << 4) + j);
                ushort4 v = *(const ushort4*)&xb[c * D + 4 * ql];   // 8B
                s.x += bf2f(v.x); s.y += bf2f(v.y);
                s.z += bf2f(v.z); s.w += bf2f(v.w);
            }
        }
        float dinv = (deg > 0) ? 1.0f / (float)deg : 0.0f;
        short4 mv;
        mv.x = (short)f2bf(s.x * dinv); mv.y = (short)f2bf(s.y * dinv);
        mv.z = (short)f2bf(s.z * dinv); mv.w = (short)f2bf(s.w * dinv);
        *(short4*)&mtile[w][p * 4 + q4][4 * ql] = mv;   // 8B, wave-local
    }

    // ---- A fragments: ks 0,1 direct bf16 from xb; ks 2,3 from mean LDS -----
    int nrow = tile + m_;
    const unsigned short* xr = xb + (size_t)(nrow < N ? nrow : 0) * D;
    bf16x8 afrag[4];
    afrag[0] = *(const bf16x8*)&xr[quad * 8];
    afrag[1] = *(const bf16x8*)&xr[32 + quad * 8];
    #pragma unroll
    for (int ks = 2; ks < 4; ++ks)
        afrag[ks] = *(const bf16x8*)&mtile[w][m_][(ks - 2) * 32 + quad * 8];

    // ---- MFMA: 4 f-tiles x 4 k-steps ----
    f32x4 acc[4];
    #pragma unroll
    for (int nf = 0; nf < 4; ++nf) {
        int fcol = nf * 16 + m_;
        float bsum = bs[fcol] + bn[fcol];
        acc[nf] = (f32x4){bsum, bsum, bsum, bsum};
    }
    #pragma unroll
    for (int nf = 0; nf < 4; ++nf) {
        #pragma unroll
        for (int ks = 0; ks < 4; ++ks) {
            bf16x8 bfr = *(const bf16x8*)&wcat[nf * 16 + m_][ks * 32 + quad * 8];
            acc[nf] = __builtin_amdgcn_mfma_f32_16x16x32_bf16(
                afrag[ks], bfr, acc[nf], 0, 0, 0);
        }
    }

    // ---- store: row = quad*4 + reg, col = nf*16 + m_ ----
    #pragma unroll
    for (int nf = 0; nf < 4; ++nf) {
        int fcol = nf * 16 + m_;
        #pragma unroll
        for (int r = 0; r < 4; ++r) {
            int node = tile + quad * 4 + r;
            if (node < N) out[(size_t)node * D + fcol] = acc[nf][r];
        }
    }
}

// ================= host launcher ============================================
extern "C" void kernel_launch(void* const* d_in, const int* in_sizes, int n_in,
                              void* d_out, int out_size, void* d_ws, size_t ws_size,
                              hipStream_t stream) {
    const float* x  = (const float*)d_in[0];
    const void*  ei = d_in[1];
    const float* Ws = (const float*)d_in[2];
    const float* bs = (const float*)d_in[3];
    const float* Wn = (const float*)d_in[4];
    const float* bn = (const float*)d_in[5];
    float* out = (float*)d_out;

    int N = in_sizes[0] / D;
    int E = in_sizes[1] / 2;

    unsigned short* xb    = (unsigned short*)d_ws;          // N*D
    unsigned short* slots = xb + (size_t)N * D;             // N*CAP
    int*            cnt   = (int*)(slots + (size_t)N * CAP);

    hipMemsetAsync(cnt, 0, (size_t)N * sizeof(int), stream);   // DMA, ~2 us

    build_k<<<784, 256, 0, stream>>>(x, ei, cnt, slots, xb, N, E);

    int ntiles  = (N + TPW - 1) / TPW;        // 3125
    int fblocks = (ntiles + WPB - 1) / WPB;   // 782
    fused_k<<<fblocks, TPB, 0, stream>>>(xb, cnt, slots, Ws, bs, Wn, bn, out, N);
}